// Round 1
// baseline (256.301 us; speedup 1.0000x reference)
//
#include <hip/hip_runtime.h>
#include <cstdint>
#include <cstddef>

typedef unsigned short ushort_t;
typedef __attribute__((ext_vector_type(4))) float f32x4;
typedef __attribute__((ext_vector_type(8))) short s16x8;

#define PI_4F 0.78539816339744830962f

// round-to-nearest-even fp32 -> bf16
__device__ inline ushort_t f2bf(float f) {
  unsigned int u = __float_as_uint(f);
  u = u + 0x7fffu + ((u >> 16) & 1u);
  return (ushort_t)(u >> 16);
}

// ---------------------------------------------------------------------------
// Kernel 1: rot matrices. 64 threads, one per (b, n) pair. rot[bn][81] fp32.
// ---------------------------------------------------------------------------
__global__ void rot_kernel(const float* __restrict__ thetas, const float* __restrict__ scales,
                           const float* __restrict__ lambdas, float* __restrict__ rot) {
  int tid = threadIdx.x;  // 0..63 == b*4 + n
  float t = thetas[tid], s = scales[tid], lam = lambdas[tid];
  float xv = cosf(t) * s, yv = sinf(t) * s;
  bool pos = (t >= 0.0f), big = (s >= 1.0f), m1 = (fabsf(t) <= PI_4F);
  float M[81];
#pragma unroll
  for (int i = 0; i < 81; ++i) M[i] = 0.0f;
  M[36 + 4] = 1.0f;  // center row
  if (pos) {
    float a = xv - yv, bb = xv * yv, c = xv + yv;
    if (m1 && big) {  // pb1
      M[0] = a; M[1] = 1 - a;
      M[9 + 1] = 1 - yv; M[9 + 2] = yv;
      M[18 + 2] = a; M[18 + 5] = 1 - a;
      M[27 + 0] = yv; M[27 + 3] = 1 - yv;
      M[45 + 5] = 1 - yv; M[45 + 8] = yv;
      M[54 + 3] = 1 - a; M[54 + 6] = a;
      M[63 + 6] = yv; M[63 + 7] = 1 - yv;
      M[72 + 7] = 1 - a; M[72 + 8] = a;
    } else if (m1) {  // ps1 (small, |t|<=pi/4)
      float d = a * c, e = a + c;
      M[0] = d; M[1] = a - d; M[3] = c - d; M[4] = 1 - e + d;
      M[9 + 1] = xv - bb; M[9 + 2] = bb; M[9 + 4] = 1 - c + bb; M[9 + 5] = yv - bb;
      M[18 + 1] = c - d; M[18 + 2] = d; M[18 + 4] = 1 - e + d; M[18 + 5] = a - d;
      M[27 + 0] = bb; M[27 + 1] = yv - bb; M[27 + 3] = xv - bb; M[27 + 4] = 1 - c + bb;
      M[45 + 4] = 1 - c + bb; M[45 + 5] = xv - bb; M[45 + 7] = yv - bb; M[45 + 8] = bb;
      M[54 + 3] = a - d; M[54 + 4] = 1 - e + d; M[54 + 6] = d; M[54 + 7] = c - d;
      M[63 + 3] = yv - bb; M[63 + 4] = 1 - c + bb; M[63 + 6] = bb; M[63 + 7] = xv - bb;
      M[72 + 4] = 1 - e + d; M[72 + 5] = c - d; M[72 + 7] = a - d; M[72 + 8] = d;
    } else {  // pb2 == ps2
      M[0] = a; M[1] = 1 - a;
      M[9 + 1] = xv - bb; M[9 + 2] = bb; M[9 + 4] = 1 - c + bb; M[9 + 5] = yv - bb;
      M[18 + 2] = a; M[18 + 5] = 1 - a;
      M[27 + 0] = bb; M[27 + 1] = yv - bb; M[27 + 3] = xv - bb; M[27 + 4] = 1 - c + bb;
      M[45 + 4] = 1 - c + bb; M[45 + 5] = xv - bb; M[45 + 7] = yv - bb; M[45 + 8] = bb;
      M[54 + 3] = 1 - a; M[54 + 6] = a;
      M[63 + 3] = yv - bb; M[63 + 4] = 1 - c + bb; M[63 + 6] = bb; M[63 + 7] = xv - bb;
      M[72 + 7] = 1 - a; M[72 + 8] = a;
    }
  } else {
    float yp = -yv;
    float ap = xv - yp, bp = xv * yp, cp = xv + yp;
    if (m1 && big) {  // nb1
      M[0] = cp; M[3] = 1 - cp;
      M[9 + 0] = yp; M[9 + 1] = 1 - yp;
      M[18 + 1] = 1 - cp; M[18 + 2] = cp;
      M[27 + 3] = 1 - yp; M[27 + 6] = yp;
      M[45 + 2] = yp; M[45 + 5] = 1 - yp;
      M[54 + 6] = cp; M[54 + 7] = 1 - cp;
      M[63 + 7] = 1 - yp; M[63 + 8] = yp;
      M[72 + 5] = 1 - cp; M[72 + 8] = cp;
    } else if (m1) {  // ns1
      float dp = ap * cp, ep = ap + cp;
      M[0] = dp; M[1] = cp - dp; M[3] = ap - dp; M[4] = 1 - ep + dp;
      M[9 + 0] = bp; M[9 + 1] = xv - bp; M[9 + 3] = yp - bp; M[9 + 4] = 1 - cp + bp;
      M[18 + 1] = ap - dp; M[18 + 2] = dp; M[18 + 4] = 1 - ep + dp; M[18 + 5] = cp - dp;
      M[27 + 1] = yp - bp; M[27 + 2] = bp; M[27 + 4] = 1 - cp + bp; M[27 + 5] = xv - bp;
      M[45 + 3] = xv - bp; M[45 + 4] = 1 - cp + bp; M[45 + 6] = bp; M[45 + 7] = yp - bp;
      M[54 + 3] = cp - dp; M[54 + 4] = 1 - ep + dp; M[54 + 6] = dp; M[54 + 7] = ap - dp;
      M[63 + 4] = 1 - cp + bp; M[63 + 5] = yp - bp; M[63 + 7] = xv - bp; M[63 + 8] = bp;
      M[72 + 4] = 1 - ep + dp; M[72 + 5] = ap - dp; M[72 + 7] = cp - dp; M[72 + 8] = dp;
    } else {  // nb2 == ns2
      M[0] = cp; M[3] = 1 - cp;
      M[9 + 0] = bp; M[9 + 1] = xv - bp; M[9 + 3] = yp - bp; M[9 + 4] = 1 - cp + bp;
      M[18 + 1] = 1 - cp; M[18 + 2] = cp;
      M[27 + 3] = xv - bp; M[27 + 4] = 1 - cp + bp; M[27 + 6] = bp; M[27 + 7] = yp - bp;
      M[45 + 1] = yp - bp; M[45 + 2] = bp; M[45 + 4] = 1 - cp + bp; M[45 + 5] = xv - bp;
      M[54 + 6] = cp; M[54 + 7] = 1 - cp;
      M[63 + 4] = 1 - cp + bp; M[63 + 5] = yp - bp; M[63 + 7] = xv - bp; M[63 + 8] = bp;
      M[72 + 5] = 1 - cp; M[72 + 8] = cp;
    }
  }
  float* r = rot + tid * 81;
#pragma unroll
  for (int i = 0; i < 81; ++i) r[i] = M[i] * lam;
}

// ---------------------------------------------------------------------------
// Kernel 2: per-sample transformed weights.
// Wt[b][i][o][c] (bf16) = sum_n sum_j rot[b,n,i,j] * weight[n,o,c,j]
// Grid: 256 blocks (one per o), 256 threads (one per c).
// ---------------------------------------------------------------------------
__global__ void wt_kernel(const float* __restrict__ weight, const float* __restrict__ rot,
                          ushort_t* __restrict__ wtout) {
  __shared__ float rs[64 * 81];
  const int o = blockIdx.x;
  const int c = threadIdx.x;
  for (int i = threadIdx.x; i < 64 * 81; i += 256) rs[i] = rot[i];
  float wv[4][9];
#pragma unroll
  for (int n = 0; n < 4; ++n) {
    const float* wp = weight + (((size_t)(n * 256 + o)) * 256 + c) * 9;
#pragma unroll
    for (int j = 0; j < 9; ++j) wv[n][j] = wp[j];
  }
  __syncthreads();
  for (int b = 0; b < 16; ++b) {
#pragma unroll
    for (int i = 0; i < 9; ++i) {
      float acc = 0.0f;
#pragma unroll
      for (int n = 0; n < 4; ++n) {
        const float* r = &rs[(b * 4 + n) * 81 + i * 9];
#pragma unroll
        for (int j = 0; j < 9; ++j) acc = fmaf(r[j], wv[n][j], acc);
      }
      wtout[((size_t)((b * 9 + i) * 256 + o)) * 256 + c] = f2bf(acc);
    }
  }
}

// ---------------------------------------------------------------------------
// Kernel 3a: zero-fill xpad (borders must be zero; fill everything, it's ~6us)
// ---------------------------------------------------------------------------
__global__ void fill_zero(uint4* __restrict__ p) {
  p[(size_t)blockIdx.x * 256 + threadIdx.x] = make_uint4(0u, 0u, 0u, 0u);
}

// ---------------------------------------------------------------------------
// Kernel 3b: x [b][c][h][w] fp32 -> xpad [b][h+1][w+1][c] bf16 (66x66 padded)
// ---------------------------------------------------------------------------
__global__ void transpose_kernel(const float* __restrict__ x, ushort_t* __restrict__ xpad) {
  __shared__ float tile[32][33];
  const int b = blockIdx.z, ct = blockIdx.y, st = blockIdx.x;
  const int tx = threadIdx.x & 31, ty = threadIdx.x >> 5;  // ty 0..7
  const int hw0 = st * 32, c0 = ct * 32;
  const float* xb = x + ((size_t)(b * 256 + c0)) * 4096 + hw0;
#pragma unroll
  for (int j = 0; j < 4; ++j)
    tile[ty + j * 8][tx] = xb[(size_t)(ty + j * 8) * 4096 + tx];
  __syncthreads();
#pragma unroll
  for (int j = 0; j < 4; ++j) {
    int s = ty + j * 8;
    int hw = hw0 + s;
    int h = hw >> 6, w = hw & 63;
    xpad[((size_t)(b * 4356 + (h + 1) * 66 + (w + 1))) * 256 + c0 + tx] = f2bf(tile[tx][s]);
  }
}

// ---------------------------------------------------------------------------
// Kernel 4: implicit-GEMM conv, bf16 MFMA (m97 structure).
// Per batch b: C[o, hw] = sum_{tap, c} Wt[b][tap][o][c] * xpad[b][h+kh][w+kw][c]
// Block: 128 o x 128 hw tile, BK=32, 72 K-steps. 256 threads = 4 waves,
// wave (wm, wn) owns a 64x64 quadrant as 4x4 MFMA 16x16x32 tiles.
// ---------------------------------------------------------------------------
__device__ inline void gload16(const ushort_t* g, ushort_t* l) {
  __builtin_amdgcn_global_load_lds(
      (const __attribute__((address_space(1))) unsigned int*)g,
      (__attribute__((address_space(3))) unsigned int*)l, 16, 0, 0);
}

__global__ void conv_kernel(const ushort_t* __restrict__ xpad, const ushort_t* __restrict__ wt,
                            float* __restrict__ out) {
  __shared__ __align__(16) ushort_t As[128 * 32];  // [o_local][k]  8 KB
  __shared__ __align__(16) ushort_t Bs[128 * 32];  // [n_local][k]  8 KB
  const int ntile = blockIdx.x;  // 0..31 -> 128 spatial positions (2 rows)
  const int mtile = blockIdx.y;  // 0..1  -> 128 output channels
  const int b = blockIdx.z;      // 0..15
  const int t = threadIdx.x;
  const int wave = t >> 6, lane = t & 63;
  const int wm = wave & 1, wn = wave >> 1;
  const int lr = lane & 15, lq = lane >> 4;
  const int o0 = mtile * 128, h0 = ntile * 2;

  const ushort_t* wt_b = wt + (size_t)b * 589824;    // 9*256*256
  const ushort_t* xp_b = xpad + (size_t)b * 1115136; // 4356*256

  const int lrow = t >> 2;        // 0..63: row handled by this thread (first call)
  const int lco = (t & 3) * 8;    // channel offset (8 bf16 = 16 B per lane)

  // wave-uniform LDS bases; lane l writes at base + l*16 B  (= l*8 elements)
  ushort_t* As0 = As + wave * 512;
  ushort_t* As1 = As + 2048 + wave * 512;
  ushort_t* Bs0 = Bs + wave * 512;
  ushort_t* Bs1 = Bs + 2048 + wave * 512;

  f32x4 acc[4][4];
#pragma unroll
  for (int i = 0; i < 4; ++i)
#pragma unroll
    for (int j = 0; j < 4; ++j) acc[i][j] = (f32x4)(0.0f);

  for (int ks = 0; ks < 72; ++ks) {
    const int tap = ks >> 3;          // 0..8
    const int c0 = (ks & 7) << 5;     // 0,32,..,224
    const int kh = tap / 3, kw = tap - kh * 3;

    __syncthreads();  // previous iteration's LDS reads done
    {
      // A tile: Wt[b][tap][o0 .. o0+127][c0 .. c0+31]
      const ushort_t* ga = wt_b + ((size_t)(tap * 256 + o0 + lrow)) * 256 + c0 + lco;
      gload16(ga, As0);
      gload16(ga + 64 * 256, As1);
      // B tile: xpad rows h0+kh and h0+1+kh, cols w+kw, channels c0..c0+31
      const int sp0 = (h0 + kh) * 66 + lrow + kw;
      const ushort_t* gb = xp_b + (size_t)sp0 * 256 + c0 + lco;
      gload16(gb, Bs0);
      gload16(gb + 66 * 256, Bs1);
    }
    asm volatile("s_waitcnt vmcnt(0)" ::: "memory");
    __syncthreads();  // all waves' tiles resident

    s16x8 af[4], bfr[4];
#pragma unroll
    for (int mi = 0; mi < 4; ++mi)
      af[mi] = *(const s16x8*)(As + ((wm * 64 + mi * 16 + lr) * 32 + lq * 8));
#pragma unroll
    for (int ni = 0; ni < 4; ++ni)
      bfr[ni] = *(const s16x8*)(Bs + ((wn * 64 + ni * 16 + lr) * 32 + lq * 8));
#pragma unroll
    for (int mi = 0; mi < 4; ++mi)
#pragma unroll
      for (int ni = 0; ni < 4; ++ni)
        acc[mi][ni] = __builtin_amdgcn_mfma_f32_16x16x32_bf16(af[mi], bfr[ni], acc[mi][ni], 0, 0, 0);
  }

  // Epilogue. C/D layout (m89-verified): col(n) = lane&15, row(m) = (lane>>4)*4 + reg
  float* ob = out + ((size_t)(b * 256 + o0 + wm * 64)) * 4096 + ntile * 128 + wn * 64 + lr;
#pragma unroll
  for (int mi = 0; mi < 4; ++mi)
#pragma unroll
    for (int r = 0; r < 4; ++r) {
      float* orow = ob + (size_t)(mi * 16 + lq * 4 + r) * 4096;
#pragma unroll
      for (int ni = 0; ni < 4; ++ni) orow[ni * 16] = acc[mi][ni][r];
    }
}

// ---------------------------------------------------------------------------
extern "C" void kernel_launch(void* const* d_in, const int* in_sizes, int n_in,
                              void* d_out, int out_size, void* d_ws, size_t ws_size,
                              hipStream_t stream) {
  const float* x = (const float*)d_in[0];       // [16,256,64,64]
  const float* thetas = (const float*)d_in[1];  // [16,4]
  const float* scales = (const float*)d_in[2];  // [16,4]
  const float* lambdas = (const float*)d_in[3]; // [16,4]
  const float* weight = (const float*)d_in[4];  // [4,256,256,3,3]
  float* out = (float*)d_out;                   // [16,256,64,64]

  // workspace layout (52.1 MB total):
  //   rot  fp32 [64][81]            @ 0        (20736 B, padded to 32 KB)
  //   Wt   bf16 [16][9][256][256]   @ 32768    (18874368 B)
  //   xpad bf16 [16][66][66][256]   @ 18907136 (35684352 B)
  float* rot_ws = (float*)d_ws;
  ushort_t* wt_ws = (ushort_t*)((char*)d_ws + 32768);
  ushort_t* xpad_ws = (ushort_t*)((char*)d_ws + 32768 + 18874368);

  rot_kernel<<<1, 64, 0, stream>>>(thetas, scales, lambdas, rot_ws);
  wt_kernel<<<256, 256, 0, stream>>>(weight, rot_ws, wt_ws);
  fill_zero<<<8712, 256, 0, stream>>>((uint4*)xpad_ws);  // 8712*256*16 B = 35684352
  transpose_kernel<<<dim3(128, 8, 16), 256, 0, stream>>>(x, xpad_ws);
  conv_kernel<<<dim3(32, 2, 16), 256, 0, stream>>>(xpad_ws, wt_ws, out);
}

// Round 2
// 241.933 us; speedup vs baseline: 1.0594x; 1.0594x over previous
//
#include <hip/hip_runtime.h>
#include <cstdint>
#include <cstddef>

typedef unsigned short ushort_t;
typedef __attribute__((ext_vector_type(4))) float f32x4;
typedef __attribute__((ext_vector_type(8))) short s16x8;

#define PI_4F 0.78539816339744830962f

// round-to-nearest-even fp32 -> bf16
__device__ inline ushort_t f2bf(float f) {
  unsigned int u = __float_as_uint(f);
  u = u + 0x7fffu + ((u >> 16) & 1u);
  return (ushort_t)(u >> 16);
}

// ---------------------------------------------------------------------------
// Kernel 1: per-sample transformed weights, with rot-matrix computation fused.
// Wt[b][i][o][c] (bf16) = sum_n sum_j rot[b,n,i,j] * weight[n,o,c,j]
// Grid: 256 blocks (one per o), 256 threads (one per c).
// Threads 0..63 first compute rot[bn][81]*lambda into LDS.
// ---------------------------------------------------------------------------
__global__ void wt_kernel(const float* __restrict__ weight,
                          const float* __restrict__ thetas, const float* __restrict__ scales,
                          const float* __restrict__ lambdas, ushort_t* __restrict__ wtout) {
  __shared__ float rs[64 * 81];
  const int o = blockIdx.x;
  const int c = threadIdx.x;

  if (threadIdx.x < 64) {
    int tid = threadIdx.x;  // b*4 + n
    float t = thetas[tid], s = scales[tid], lam = lambdas[tid];
    float xv = cosf(t) * s, yv = sinf(t) * s;
    bool pos = (t >= 0.0f), big = (s >= 1.0f), m1 = (fabsf(t) <= PI_4F);
    float M[81];
#pragma unroll
    for (int i = 0; i < 81; ++i) M[i] = 0.0f;
    M[36 + 4] = 1.0f;
    if (pos) {
      float a = xv - yv, bb = xv * yv, cc = xv + yv;
      if (m1 && big) {  // pb1
        M[0] = a; M[1] = 1 - a;
        M[9 + 1] = 1 - yv; M[9 + 2] = yv;
        M[18 + 2] = a; M[18 + 5] = 1 - a;
        M[27 + 0] = yv; M[27 + 3] = 1 - yv;
        M[45 + 5] = 1 - yv; M[45 + 8] = yv;
        M[54 + 3] = 1 - a; M[54 + 6] = a;
        M[63 + 6] = yv; M[63 + 7] = 1 - yv;
        M[72 + 7] = 1 - a; M[72 + 8] = a;
      } else if (m1) {  // ps1
        float d = a * cc, e = a + cc;
        M[0] = d; M[1] = a - d; M[3] = cc - d; M[4] = 1 - e + d;
        M[9 + 1] = xv - bb; M[9 + 2] = bb; M[9 + 4] = 1 - cc + bb; M[9 + 5] = yv - bb;
        M[18 + 1] = cc - d; M[18 + 2] = d; M[18 + 4] = 1 - e + d; M[18 + 5] = a - d;
        M[27 + 0] = bb; M[27 + 1] = yv - bb; M[27 + 3] = xv - bb; M[27 + 4] = 1 - cc + bb;
        M[45 + 4] = 1 - cc + bb; M[45 + 5] = xv - bb; M[45 + 7] = yv - bb; M[45 + 8] = bb;
        M[54 + 3] = a - d; M[54 + 4] = 1 - e + d; M[54 + 6] = d; M[54 + 7] = cc - d;
        M[63 + 3] = yv - bb; M[63 + 4] = 1 - cc + bb; M[63 + 6] = bb; M[63 + 7] = xv - bb;
        M[72 + 4] = 1 - e + d; M[72 + 5] = cc - d; M[72 + 7] = a - d; M[72 + 8] = d;
      } else {  // pb2 == ps2
        M[0] = a; M[1] = 1 - a;
        M[9 + 1] = xv - bb; M[9 + 2] = bb; M[9 + 4] = 1 - cc + bb; M[9 + 5] = yv - bb;
        M[18 + 2] = a; M[18 + 5] = 1 - a;
        M[27 + 0] = bb; M[27 + 1] = yv - bb; M[27 + 3] = xv - bb; M[27 + 4] = 1 - cc + bb;
        M[45 + 4] = 1 - cc + bb; M[45 + 5] = xv - bb; M[45 + 7] = yv - bb; M[45 + 8] = bb;
        M[54 + 3] = 1 - a; M[54 + 6] = a;
        M[63 + 3] = yv - bb; M[63 + 4] = 1 - cc + bb; M[63 + 6] = bb; M[63 + 7] = xv - bb;
        M[72 + 7] = 1 - a; M[72 + 8] = a;
      }
    } else {
      float yp = -yv;
      float ap = xv - yp, bp = xv * yp, cp = xv + yp;
      if (m1 && big) {  // nb1
        M[0] = cp; M[3] = 1 - cp;
        M[9 + 0] = yp; M[9 + 1] = 1 - yp;
        M[18 + 1] = 1 - cp; M[18 + 2] = cp;
        M[27 + 3] = 1 - yp; M[27 + 6] = yp;
        M[45 + 2] = yp; M[45 + 5] = 1 - yp;
        M[54 + 6] = cp; M[54 + 7] = 1 - cp;
        M[63 + 7] = 1 - yp; M[63 + 8] = yp;
        M[72 + 5] = 1 - cp; M[72 + 8] = cp;
      } else if (m1) {  // ns1
        float dp = ap * cp, ep = ap + cp;
        M[0] = dp; M[1] = cp - dp; M[3] = ap - dp; M[4] = 1 - ep + dp;
        M[9 + 0] = bp; M[9 + 1] = xv - bp; M[9 + 3] = yp - bp; M[9 + 4] = 1 - cp + bp;
        M[18 + 1] = ap - dp; M[18 + 2] = dp; M[18 + 4] = 1 - ep + dp; M[18 + 5] = cp - dp;
        M[27 + 1] = yp - bp; M[27 + 2] = bp; M[27 + 4] = 1 - cp + bp; M[27 + 5] = xv - bp;
        M[45 + 3] = xv - bp; M[45 + 4] = 1 - cp + bp; M[45 + 6] = bp; M[45 + 7] = yp - bp;
        M[54 + 3] = cp - dp; M[54 + 4] = 1 - ep + dp; M[54 + 6] = dp; M[54 + 7] = ap - dp;
        M[63 + 4] = 1 - cp + bp; M[63 + 5] = yp - bp; M[63 + 7] = xv - bp; M[63 + 8] = bp;
        M[72 + 4] = 1 - ep + dp; M[72 + 5] = ap - dp; M[72 + 7] = cp - dp; M[72 + 8] = dp;
      } else {  // nb2 == ns2
        M[0] = cp; M[3] = 1 - cp;
        M[9 + 0] = bp; M[9 + 1] = xv - bp; M[9 + 3] = yp - bp; M[9 + 4] = 1 - cp + bp;
        M[18 + 1] = 1 - cp; M[18 + 2] = cp;
        M[27 + 3] = xv - bp; M[27 + 4] = 1 - cp + bp; M[27 + 6] = bp; M[27 + 7] = yp - bp;
        M[45 + 1] = yp - bp; M[45 + 2] = bp; M[45 + 4] = 1 - cp + bp; M[45 + 5] = xv - bp;
        M[54 + 6] = cp; M[54 + 7] = 1 - cp;
        M[63 + 4] = 1 - cp + bp; M[63 + 5] = yp - bp; M[63 + 7] = xv - bp; M[63 + 8] = bp;
        M[72 + 5] = 1 - cp; M[72 + 8] = cp;
      }
    }
    float* r = rs + tid * 81;
#pragma unroll
    for (int i = 0; i < 81; ++i) r[i] = M[i] * lam;
  }

  float wv[4][9];
#pragma unroll
  for (int n = 0; n < 4; ++n) {
    const float* wp = weight + (((size_t)(n * 256 + o)) * 256 + c) * 9;
#pragma unroll
    for (int j = 0; j < 9; ++j) wv[n][j] = wp[j];
  }
  __syncthreads();
  for (int b = 0; b < 16; ++b) {
#pragma unroll
    for (int i = 0; i < 9; ++i) {
      float acc = 0.0f;
#pragma unroll
      for (int n = 0; n < 4; ++n) {
        const float* r = &rs[(b * 4 + n) * 81 + i * 9];
#pragma unroll
        for (int j = 0; j < 9; ++j) acc = fmaf(r[j], wv[n][j], acc);
      }
      wtout[((size_t)((b * 9 + i) * 256 + o)) * 256 + c] = f2bf(acc);
    }
  }
}

// ---------------------------------------------------------------------------
// Kernel 2a: zero only the xpad border (260 positions x 256 ch per batch)
// ---------------------------------------------------------------------------
__global__ void border_zero(ushort_t* __restrict__ xpad) {
  const int p = blockIdx.x, b = blockIdx.y;
  int h, w;
  if (p < 66) { h = 0; w = p; }
  else if (p < 132) { h = 65; w = p - 66; }
  else if (p < 196) { w = 0; h = p - 131; }   // h = 1..64
  else { w = 65; h = p - 195; }               // h = 1..64
  size_t base = ((size_t)(b * 4356 + h * 66 + w)) * 256 + threadIdx.x * 4;
  *(uint2*)(xpad + base) = make_uint2(0u, 0u);
}

// ---------------------------------------------------------------------------
// Kernel 2b: x [b][c][h][w] fp32 -> xpad [b][h+1][w+1][c] bf16 (66x66 padded)
// ---------------------------------------------------------------------------
__global__ void transpose_kernel(const float* __restrict__ x, ushort_t* __restrict__ xpad) {
  __shared__ float tile[32][33];
  const int b = blockIdx.z, ct = blockIdx.y, st = blockIdx.x;
  const int tx = threadIdx.x & 31, ty = threadIdx.x >> 5;  // ty 0..7
  const int hw0 = st * 32, c0 = ct * 32;
  const float* xb = x + ((size_t)(b * 256 + c0)) * 4096 + hw0;
#pragma unroll
  for (int j = 0; j < 4; ++j)
    tile[ty + j * 8][tx] = xb[(size_t)(ty + j * 8) * 4096 + tx];
  __syncthreads();
#pragma unroll
  for (int j = 0; j < 4; ++j) {
    int s = ty + j * 8;
    int hw = hw0 + s;
    int h = hw >> 6, w = hw & 63;
    xpad[((size_t)(b * 4356 + (h + 1) * 66 + (w + 1))) * 256 + c0 + tx] = f2bf(tile[tx][s]);
  }
}

// ---------------------------------------------------------------------------
// Kernel 3: implicit-GEMM conv, bf16 MFMA.
// Per batch b: C[o, hw] = sum_{tap, c} Wt[b][tap][o][c] * xpad[b][h+kh][w+kw][c]
// 128x128 block tile, BK=32, 72 K-steps, double-buffered LDS (1 barrier/step).
// LDS XOR swizzle: global chunk cg (16B) of row r stored at chunk cg^((r>>1)&3)
//  -> write side stays wave-uniform global_load_lds (permute lane->global addr)
//  -> read side hits each 16B bank slot exactly 8x per wave (2-way, free).
// XCD-aware linear grid: each XCD (id&7) owns 4 (b,mtile) pairs so every
// A/B panel is fetched into exactly one XCD's L2.
// ---------------------------------------------------------------------------
__device__ inline void gload16(const ushort_t* g, ushort_t* l) {
  __builtin_amdgcn_global_load_lds(
      (const __attribute__((address_space(1))) unsigned int*)g,
      (__attribute__((address_space(3))) unsigned int*)l, 16, 0, 0);
}

__global__ __launch_bounds__(256, 4) void conv_kernel(
    const ushort_t* __restrict__ xpad, const ushort_t* __restrict__ wt,
    float* __restrict__ out) {
  __shared__ __align__(16) ushort_t As[2][128 * 32];  // 2 x 8 KB
  __shared__ __align__(16) ushort_t Bs[2][128 * 32];  // 2 x 8 KB

  // XCD-aware decode of linear block id
  const int id = blockIdx.x;
  const int xcd = id & 7;
  const int j = id >> 3;              // 0..127 within XCD
  const int P = xcd * 4 + (j >> 5);   // 0..31 (b,mtile) pair
  const int b = P >> 1, mtile = P & 1;
  const int ntile = j & 31;

  const int t = threadIdx.x;
  const int wave = t >> 6, lane = t & 63;
  const int wm = wave & 1, wn = wave >> 1;
  const int lr = lane & 15, lq = lane >> 4;
  const int o0 = mtile * 128, h0 = ntile * 2;

  const ushort_t* wt_b = wt + (size_t)b * 589824;     // 9*256*256
  const ushort_t* xp_b = xpad + (size_t)b * 1115136;  // 4356*256

  const int lrow = t >> 2;                          // 0..63 row within half-tile
  const int cg8 = (((t & 3) ^ ((t >> 3) & 3)) * 8); // swizzled global chunk (elems)

  // read-side swizzle: storage chunk for k-chunk lq of row m is lq^((m>>1)&3);
  // (m>>1)&3 == (lr>>1)&3 for all mi/wm since those add multiples of 8.
  const int rsw = (lr >> 1) & 3;
  const int aoff = (wm * 64 + lr) * 32 + (lq ^ rsw) * 8;
  const int boff = (wn * 64 + lr) * 32 + (lq ^ rsw) * 8;

  f32x4 acc[4][4];
#pragma unroll
  for (int i = 0; i < 4; ++i)
#pragma unroll
    for (int jj = 0; jj < 4; ++jj) acc[i][jj] = (f32x4)(0.0f);

  auto stage = [&](int ks, int buf) {
    const int tap = ks >> 3;
    const int c0k = (ks & 7) << 5;
    const int kh = tap / 3, kw = tap - kh * 3;
    const ushort_t* ga = wt_b + ((size_t)(tap * 256 + o0 + lrow)) * 256 + c0k + cg8;
    gload16(ga, &As[buf][wave * 512]);
    gload16(ga + 64 * 256, &As[buf][2048 + wave * 512]);
    const ushort_t* gb = xp_b + ((size_t)((h0 + kh) * 66 + lrow + kw)) * 256 + c0k + cg8;
    gload16(gb, &Bs[buf][wave * 512]);
    gload16(gb + 66 * 256, &Bs[buf][2048 + wave * 512]);
  };

  stage(0, 0);

  for (int ks = 0; ks < 72; ++ks) {
    const int buf = ks & 1;
    asm volatile("s_waitcnt vmcnt(0)" ::: "memory");
    __syncthreads();  // buf's tiles resident; prev step's LDS reads drained
    if (ks < 71) stage(ks + 1, buf ^ 1);

    const ushort_t* Ab = &As[buf][0];
    const ushort_t* Bb = &Bs[buf][0];
    s16x8 af[4], bfr[4];
#pragma unroll
    for (int mi = 0; mi < 4; ++mi)
      af[mi] = *(const s16x8*)(Ab + aoff + mi * 512);
#pragma unroll
    for (int ni = 0; ni < 4; ++ni)
      bfr[ni] = *(const s16x8*)(Bb + boff + ni * 512);
#pragma unroll
    for (int mi = 0; mi < 4; ++mi)
#pragma unroll
      for (int ni = 0; ni < 4; ++ni)
        acc[mi][ni] = __builtin_amdgcn_mfma_f32_16x16x32_bf16(af[mi], bfr[ni], acc[mi][ni], 0, 0, 0);
  }

  // Epilogue. C/D layout (m89): col(n) = lane&15, row(m) = (lane>>4)*4 + reg
  float* ob = out + ((size_t)(b * 256 + o0 + wm * 64)) * 4096 + ntile * 128 + wn * 64 + lr;
#pragma unroll
  for (int mi = 0; mi < 4; ++mi)
#pragma unroll
    for (int r = 0; r < 4; ++r) {
      float* orow = ob + (size_t)(mi * 16 + lq * 4 + r) * 4096;
#pragma unroll
      for (int ni = 0; ni < 4; ++ni) orow[ni * 16] = acc[mi][ni][r];
    }
}

// ---------------------------------------------------------------------------
extern "C" void kernel_launch(void* const* d_in, const int* in_sizes, int n_in,
                              void* d_out, int out_size, void* d_ws, size_t ws_size,
                              hipStream_t stream) {
  const float* x = (const float*)d_in[0];       // [16,256,64,64]
  const float* thetas = (const float*)d_in[1];  // [16,4]
  const float* scales = (const float*)d_in[2];  // [16,4]
  const float* lambdas = (const float*)d_in[3]; // [16,4]
  const float* weight = (const float*)d_in[4];  // [4,256,256,3,3]
  float* out = (float*)d_out;                   // [16,256,64,64]

  // workspace layout:
  //   Wt   bf16 [16][9][256][256]   @ 0        (18874368 B)
  //   xpad bf16 [16][66][66][256]   @ 18874368 (35684352 B)
  ushort_t* wt_ws = (ushort_t*)d_ws;
  ushort_t* xpad_ws = (ushort_t*)((char*)d_ws + 18874368);

  wt_kernel<<<256, 256, 0, stream>>>(weight, thetas, scales, lambdas, wt_ws);
  border_zero<<<dim3(260, 16), 64, 0, stream>>>(xpad_ws);
  transpose_kernel<<<dim3(128, 8, 16), 256, 0, stream>>>(x, xpad_ws);
  conv_kernel<<<1024, 256, 0, stream>>>(xpad_ws, wt_ws, out);
}

// Round 3
// 241.448 us; speedup vs baseline: 1.0615x; 1.0020x over previous
//
#include <hip/hip_runtime.h>
#include <cstdint>
#include <cstddef>

typedef unsigned short ushort_t;
typedef __attribute__((ext_vector_type(4))) float f32x4;
typedef __attribute__((ext_vector_type(8))) short s16x8;

#define PI_4F 0.78539816339744830962f

// round-to-nearest-even fp32 -> bf16
__device__ inline ushort_t f2bf(float f) {
  unsigned int u = __float_as_uint(f);
  u = u + 0x7fffu + ((u >> 16) & 1u);
  return (ushort_t)(u >> 16);
}

// ---------------------------------------------------------------------------
// Kernel 0: rot matrices -> GLOBAL fp32 (so wt_kernel reads them via the
// scalar path with uniform indices instead of per-thread LDS reads).
// 64 threads, one per (b, n) pair. rot[bn][81].
// ---------------------------------------------------------------------------
__global__ void rot_kernel(const float* __restrict__ thetas, const float* __restrict__ scales,
                           const float* __restrict__ lambdas, float* __restrict__ rot) {
  int tid = threadIdx.x;  // 0..63 == b*4 + n
  float t = thetas[tid], s = scales[tid], lam = lambdas[tid];
  float xv = cosf(t) * s, yv = sinf(t) * s;
  bool pos = (t >= 0.0f), big = (s >= 1.0f), m1 = (fabsf(t) <= PI_4F);
  float M[81];
#pragma unroll
  for (int i = 0; i < 81; ++i) M[i] = 0.0f;
  M[36 + 4] = 1.0f;
  if (pos) {
    float a = xv - yv, bb = xv * yv, c = xv + yv;
    if (m1 && big) {  // pb1
      M[0] = a; M[1] = 1 - a;
      M[9 + 1] = 1 - yv; M[9 + 2] = yv;
      M[18 + 2] = a; M[18 + 5] = 1 - a;
      M[27 + 0] = yv; M[27 + 3] = 1 - yv;
      M[45 + 5] = 1 - yv; M[45 + 8] = yv;
      M[54 + 3] = 1 - a; M[54 + 6] = a;
      M[63 + 6] = yv; M[63 + 7] = 1 - yv;
      M[72 + 7] = 1 - a; M[72 + 8] = a;
    } else if (m1) {  // ps1
      float d = a * c, e = a + c;
      M[0] = d; M[1] = a - d; M[3] = c - d; M[4] = 1 - e + d;
      M[9 + 1] = xv - bb; M[9 + 2] = bb; M[9 + 4] = 1 - c + bb; M[9 + 5] = yv - bb;
      M[18 + 1] = c - d; M[18 + 2] = d; M[18 + 4] = 1 - e + d; M[18 + 5] = a - d;
      M[27 + 0] = bb; M[27 + 1] = yv - bb; M[27 + 3] = xv - bb; M[27 + 4] = 1 - c + bb;
      M[45 + 4] = 1 - c + bb; M[45 + 5] = xv - bb; M[45 + 7] = yv - bb; M[45 + 8] = bb;
      M[54 + 3] = a - d; M[54 + 4] = 1 - e + d; M[54 + 6] = d; M[54 + 7] = c - d;
      M[63 + 3] = yv - bb; M[63 + 4] = 1 - c + bb; M[63 + 6] = bb; M[63 + 7] = xv - bb;
      M[72 + 4] = 1 - e + d; M[72 + 5] = c - d; M[72 + 7] = a - d; M[72 + 8] = d;
    } else {  // pb2 == ps2
      M[0] = a; M[1] = 1 - a;
      M[9 + 1] = xv - bb; M[9 + 2] = bb; M[9 + 4] = 1 - c + bb; M[9 + 5] = yv - bb;
      M[18 + 2] = a; M[18 + 5] = 1 - a;
      M[27 + 0] = bb; M[27 + 1] = yv - bb; M[27 + 3] = xv - bb; M[27 + 4] = 1 - c + bb;
      M[45 + 4] = 1 - c + bb; M[45 + 5] = xv - bb; M[45 + 7] = yv - bb; M[45 + 8] = bb;
      M[54 + 3] = 1 - a; M[54 + 6] = a;
      M[63 + 3] = yv - bb; M[63 + 4] = 1 - c + bb; M[63 + 6] = bb; M[63 + 7] = xv - bb;
      M[72 + 7] = 1 - a; M[72 + 8] = a;
    }
  } else {
    float yp = -yv;
    float ap = xv - yp, bp = xv * yp, cp = xv + yp;
    if (m1 && big) {  // nb1
      M[0] = cp; M[3] = 1 - cp;
      M[9 + 0] = yp; M[9 + 1] = 1 - yp;
      M[18 + 1] = 1 - cp; M[18 + 2] = cp;
      M[27 + 3] = 1 - yp; M[27 + 6] = yp;
      M[45 + 2] = yp; M[45 + 5] = 1 - yp;
      M[54 + 6] = cp; M[54 + 7] = 1 - cp;
      M[63 + 7] = 1 - yp; M[63 + 8] = yp;
      M[72 + 5] = 1 - cp; M[72 + 8] = cp;
    } else if (m1) {  // ns1
      float dp = ap * cp, ep = ap + cp;
      M[0] = dp; M[1] = cp - dp; M[3] = ap - dp; M[4] = 1 - ep + dp;
      M[9 + 0] = bp; M[9 + 1] = xv - bp; M[9 + 3] = yp - bp; M[9 + 4] = 1 - cp + bp;
      M[18 + 1] = ap - dp; M[18 + 2] = dp; M[18 + 4] = 1 - ep + dp; M[18 + 5] = cp - dp;
      M[27 + 1] = yp - bp; M[27 + 2] = bp; M[27 + 4] = 1 - cp + bp; M[27 + 5] = xv - bp;
      M[45 + 3] = xv - bp; M[45 + 4] = 1 - cp + bp; M[45 + 6] = bp; M[45 + 7] = yp - bp;
      M[54 + 3] = cp - dp; M[54 + 4] = 1 - ep + dp; M[54 + 6] = dp; M[54 + 7] = ap - dp;
      M[63 + 4] = 1 - cp + bp; M[63 + 5] = yp - bp; M[63 + 7] = xv - bp; M[63 + 8] = bp;
      M[72 + 4] = 1 - ep + dp; M[72 + 5] = ap - dp; M[72 + 7] = cp - dp; M[72 + 8] = dp;
    } else {  // nb2 == ns2
      M[0] = cp; M[3] = 1 - cp;
      M[9 + 0] = bp; M[9 + 1] = xv - bp; M[9 + 3] = yp - bp; M[9 + 4] = 1 - cp + bp;
      M[18 + 1] = 1 - cp; M[18 + 2] = cp;
      M[27 + 3] = xv - bp; M[27 + 4] = 1 - cp + bp; M[27 + 6] = bp; M[27 + 7] = yp - bp;
      M[45 + 1] = yp - bp; M[45 + 2] = bp; M[45 + 4] = 1 - cp + bp; M[45 + 5] = xv - bp;
      M[54 + 6] = cp; M[54 + 7] = 1 - cp;
      M[63 + 4] = 1 - cp + bp; M[63 + 5] = yp - bp; M[63 + 7] = xv - bp; M[63 + 8] = bp;
      M[72 + 5] = 1 - cp; M[72 + 8] = cp;
    }
  }
  float* r = rot + tid * 81;
#pragma unroll
  for (int i = 0; i < 81; ++i) r[i] = M[i] * lam;
}

// ---------------------------------------------------------------------------
// Kernel 1: Wt[b][i][o][c] (bf16) = sum_n sum_j rot[b,n,i,j] * weight[n,o,c,j]
// Grid: (256 o, 4 bgroup) = 1024 blocks (4/CU), 256 threads (c).
// rot indices are block-uniform -> scalar loads, no LDS.
// ---------------------------------------------------------------------------
__global__ void wt_kernel(const float* __restrict__ weight, const float* __restrict__ rot,
                          ushort_t* __restrict__ wtout) {
  const int o = blockIdx.x, bg = blockIdx.y;
  const int c = threadIdx.x;
  float wv[4][9];
#pragma unroll
  for (int n = 0; n < 4; ++n) {
    const float* wp = weight + (((size_t)(n * 256 + o)) * 256 + c) * 9;
#pragma unroll
    for (int j = 0; j < 9; ++j) wv[n][j] = wp[j];
  }
#pragma unroll
  for (int bl = 0; bl < 4; ++bl) {
    const int b = bg * 4 + bl;
#pragma unroll
    for (int i = 0; i < 9; ++i) {
      float acc = 0.0f;
#pragma unroll
      for (int n = 0; n < 4; ++n) {
        const float* r = rot + (b * 4 + n) * 81 + i * 9;
#pragma unroll
        for (int j = 0; j < 9; ++j) acc = fmaf(r[j], wv[n][j], acc);
      }
      wtout[((size_t)((b * 9 + i) * 256 + o)) * 256 + c] = f2bf(acc);
    }
  }
}

// ---------------------------------------------------------------------------
// Kernel 2a: zero only the xpad border (260 positions x 256 ch per batch)
// ---------------------------------------------------------------------------
__global__ void border_zero(ushort_t* __restrict__ xpad) {
  const int p = blockIdx.x, b = blockIdx.y;
  int h, w;
  if (p < 66) { h = 0; w = p; }
  else if (p < 132) { h = 65; w = p - 66; }
  else if (p < 196) { w = 0; h = p - 131; }
  else { w = 65; h = p - 195; }
  size_t base = ((size_t)(b * 4356 + h * 66 + w)) * 256 + threadIdx.x * 4;
  *(uint2*)(xpad + base) = make_uint2(0u, 0u);
}

// ---------------------------------------------------------------------------
// Kernel 2b: x [b][c][h][w] fp32 -> xpad [b][h+1][w+1][c] bf16.
// Block = 64 hw x 64 c tile; LDS holds bf16 [64 hw][65 c] (pad -> 2-way free).
// Writes are uint2 (16 lanes = 128 B contiguous).
// ---------------------------------------------------------------------------
__global__ void transpose_kernel(const float* __restrict__ x, ushort_t* __restrict__ xpad) {
  __shared__ ushort_t tile[64][65];
  const int b = blockIdx.z, ct = blockIdx.y, st = blockIdx.x;  // st = h row
  const int t = threadIdx.x;
  const int l = t & 63, wv = t >> 6;
  const int c0 = ct * 64;
  const float* xb = x + ((size_t)(b * 256 + c0)) * 4096 + st * 64;
#pragma unroll
  for (int k = 0; k < 16; ++k) {
    int c_l = wv + 4 * k;
    tile[l][c_l] = f2bf(xb[(size_t)c_l * 4096 + l]);
  }
  __syncthreads();
  const int hw_l0 = t >> 4, c4 = (t & 15) * 4;
#pragma unroll
  for (int k = 0; k < 4; ++k) {
    int w = hw_l0 + 16 * k;  // w within row, h == st
    uint2 v = *(const uint2*)&tile[w][c4];
    *(uint2*)&xpad[((size_t)(b * 4356 + (st + 1) * 66 + (w + 1))) * 256 + c0 + c4] = v;
  }
}

// ---------------------------------------------------------------------------
// Kernel 3: implicit-GEMM conv, bf16 MFMA, 3-stage software pipeline.
// Per batch b: C[o, hw] = sum_{tap, c} Wt[b][tap][o][c] * xpad[b][h+kh][w+kw][c]
// Tile: 256 o x 128 hw, BK=32, 72 K-steps. 512 blocks = exactly 2/CU (no tail).
// Pipeline: 3 LDS stages (72 KB), raw s_barrier + s_waitcnt vmcnt(6) so the
// next stage's global_load_lds stay in flight across the barrier (prefetch
// distance = 2 steps), never draining to vmcnt(0) except the peeled last step.
// XCD map: id&7 -> 2 batches per XCD; live set ~3 MB < 4 MB L2.
// LDS XOR swizzle (as R2): storage chunk = cg ^ ((row>>1)&3) -> 0 conflicts.
// ---------------------------------------------------------------------------
__device__ inline void gload16(const ushort_t* g, ushort_t* l) {
  __builtin_amdgcn_global_load_lds(
      (const __attribute__((address_space(1))) unsigned int*)g,
      (__attribute__((address_space(3))) unsigned int*)l, 16, 0, 0);
}

__global__ __launch_bounds__(256, 2) void conv_kernel(
    const ushort_t* __restrict__ xpad, const ushort_t* __restrict__ wt,
    float* __restrict__ out) {
  __shared__ __align__(16) ushort_t As[3][256 * 32];  // 3 x 16 KB
  __shared__ __align__(16) ushort_t Bs[3][128 * 32];  // 3 x 8 KB

  const int id = blockIdx.x;
  const int xcd = id & 7;
  const int j = id >> 3;                // 0..63 within XCD
  const int b = xcd * 2 + (j >> 5);     // 2 batches per XCD
  const int ntile = j & 31;

  const int t = threadIdx.x;
  const int wave = t >> 6, lane = t & 63;
  const int wm = wave & 1, wn = wave >> 1;
  const int lr = lane & 15, lq = lane >> 4;
  const int h0 = ntile * 2;

  const ushort_t* wt_b = wt + (size_t)b * 589824;     // 9*256*256
  const ushort_t* xp_b = xpad + (size_t)b * 1115136;  // 4356*256

  const int lrow = t >> 2;                           // 0..63
  const int cg8 = (((t & 3) ^ ((t >> 3) & 3)) * 8);  // swizzled global 16B chunk

  const int rsw = (lr >> 1) & 3;
  const int aoff = (wm * 128 + lr) * 32 + ((lq ^ rsw) * 8);
  const int boff = (wn * 64 + lr) * 32 + ((lq ^ rsw) * 8);

  f32x4 acc[8][4];
#pragma unroll
  for (int i = 0; i < 8; ++i)
#pragma unroll
    for (int jj = 0; jj < 4; ++jj) acc[i][jj] = (f32x4)(0.0f);

  auto stage = [&](int ks, int buf) {
    const int tap = ks >> 3;
    const int c0k = (ks & 7) << 5;
    const int kh = tap / 3, kw = tap - kh * 3;
    // A: Wt rows (o) 0..255, 4 x gload16 per thread
    const ushort_t* ga = wt_b + ((size_t)(tap * 256 + lrow)) * 256 + c0k + cg8;
    ushort_t* Ad = &As[buf][wave * 512];
#pragma unroll
    for (int a = 0; a < 4; ++a) gload16(ga + (size_t)a * 64 * 256, Ad + a * 2048);
    // B: xpad spatial rows h0+kh (+0,+1), w = lrow + kw
    const ushort_t* gb = xp_b + ((size_t)((h0 + kh) * 66 + lrow + kw)) * 256 + c0k + cg8;
    ushort_t* Bd = &Bs[buf][wave * 512];
    gload16(gb, Bd);
    gload16(gb + 66 * 256, Bd + 2048);
  };

  auto compute = [&](int buf) {
    const ushort_t* Ab = &As[buf][0];
    const ushort_t* Bb = &Bs[buf][0];
    s16x8 bfr[4];
#pragma unroll
    for (int ni = 0; ni < 4; ++ni)
      bfr[ni] = *(const s16x8*)(Bb + boff + ni * 512);
#pragma unroll
    for (int ms = 0; ms < 8; ++ms) {
      s16x8 af = *(const s16x8*)(Ab + aoff + ms * 512);
#pragma unroll
      for (int ni = 0; ni < 4; ++ni)
        acc[ms][ni] = __builtin_amdgcn_mfma_f32_16x16x32_bf16(af, bfr[ni], acc[ms][ni], 0, 0, 0);
    }
  };

  stage(0, 0);
  stage(1, 1);

  int bc = 0;  // current buffer = ks % 3
  for (int ks = 0; ks < 71; ++ks) {
    // stage(ks) complete (6 oldest loads), stage(ks+1)'s 6 stay in flight
    asm volatile("s_waitcnt vmcnt(6)" ::: "memory");
    asm volatile("s_barrier" ::: "memory");
    if (ks < 70) {
      int bp = (bc == 0) ? 2 : bc - 1;  // (ks+2) % 3
      stage(ks + 2, bp);
    }
    compute(bc);
    bc = (bc == 2) ? 0 : bc + 1;
  }
  // peeled last step: only stage(71)'s 6 loads outstanding -> full drain
  asm volatile("s_waitcnt vmcnt(0)" ::: "memory");
  asm volatile("s_barrier" ::: "memory");
  compute(bc);  // bc == 71 % 3 == 2

  // Epilogue. C/D layout (m89): col(n) = lane&15, row(m) = (lane>>4)*4 + reg
  float* ob = out + ((size_t)(b * 256 + wm * 128)) * 4096 + ntile * 128 + wn * 64 + lr;
#pragma unroll
  for (int ms = 0; ms < 8; ++ms)
#pragma unroll
    for (int r = 0; r < 4; ++r) {
      float* orow = ob + (size_t)(ms * 16 + lq * 4 + r) * 4096;
#pragma unroll
      for (int ni = 0; ni < 4; ++ni) orow[ni * 16] = acc[ms][ni][r];
    }
}

// ---------------------------------------------------------------------------
extern "C" void kernel_launch(void* const* d_in, const int* in_sizes, int n_in,
                              void* d_out, int out_size, void* d_ws, size_t ws_size,
                              hipStream_t stream) {
  const float* x = (const float*)d_in[0];       // [16,256,64,64]
  const float* thetas = (const float*)d_in[1];  // [16,4]
  const float* scales = (const float*)d_in[2];  // [16,4]
  const float* lambdas = (const float*)d_in[3]; // [16,4]
  const float* weight = (const float*)d_in[4];  // [4,256,256,3,3]
  float* out = (float*)d_out;                   // [16,256,64,64]

  // workspace layout:
  //   rot  fp32 [64][81]            @ 0        (20736 B, padded to 32 KB)
  //   Wt   bf16 [16][9][256][256]   @ 32768    (18874368 B)
  //   xpad bf16 [16][66][66][256]   @ 18907136 (35684352 B)
  float* rot_ws = (float*)d_ws;
  ushort_t* wt_ws = (ushort_t*)((char*)d_ws + 32768);
  ushort_t* xpad_ws = (ushort_t*)((char*)d_ws + 32768 + 18874368);

  rot_kernel<<<1, 64, 0, stream>>>(thetas, scales, lambdas, rot_ws);
  wt_kernel<<<dim3(256, 4), 256, 0, stream>>>(weight, rot_ws, wt_ws);
  border_zero<<<dim3(260, 16), 64, 0, stream>>>(xpad_ws);
  transpose_kernel<<<dim3(64, 4, 16), 256, 0, stream>>>(x, xpad_ws);
  conv_kernel<<<512, 256, 0, stream>>>(xpad_ws, wt_ws, out);
}